// Round 6
// baseline (24998.845 us; speedup 1.0000x reference)
//
#include <hip/hip_runtime.h>

// Decoder: 2-layer LSTM (H=256), T=512, B=256, scalar output feedback.
// Round 6: MFMA, 32 blocks x 512 threads (8 waves, pinned 2 waves/EU via
// amdgpu_waves_per_eu(2,2) -> 256-VGPR budget). Per-wave A-fragment stream
// repacked CONTIGUOUS in consumption order (48 chunks of 4 frags / step,
// step-invariant); 4-slot register ring with distance-3 prefetch (12 loads
// = 12 KB/wave in flight). M=8 batch/block for latency insurance.

namespace {

typedef _Float16 v8h __attribute__((ext_vector_type(8)));
typedef _Float16 v4h __attribute__((ext_vector_type(4)));
typedef float v4f __attribute__((ext_vector_type(4)));

constexpr int kB = 256, kT = 512, kH = 256;
constexpr int kM = 8;                              // batch per block
constexpr int kFragsPerWave = 192;                 // frags per wave per step
constexpr int kTotFrags = 8 * kFragsPerWave * 64;  // 98304 v8h
constexpr size_t kWsNeeded = (size_t)kTotFrags * sizeof(v8h);  // 1.5 MB

__device__ __forceinline__ float fsig(float v) {
  return __builtin_amdgcn_rcpf(1.f + __expf(-v));
}
__device__ __forceinline__ float ftanh(float v) {
  return 1.f - 2.f * __builtin_amdgcn_rcpf(1.f + __expf(2.f * v));
}

// Repack the three (1024x256) fp32 matrices into per-wave contiguous fp16
// A-fragment streams: dst[(w*192 + s)*64 + lane], s = mat*64 + g*8 + kt,
// g = q*2 + mt; lane holds W[q*256 + 32w + 16mt + (lane&15)]
//                            [kt*32 + (lane>>4)*8 + j], j=0..7.
__global__ __launch_bounds__(256) void pack_frag2(const float* __restrict__ s0,
                                                  const float* __restrict__ s1,
                                                  const float* __restrict__ s2,
                                                  v8h* __restrict__ dst) {
  int idx = blockIdx.x * 256 + threadIdx.x;  // 0 .. 98303
  int lane = idx & 63;
  int sw = idx >> 6;
  int s = sw % 192, w = sw / 192;
  int mat = s >> 6, u = s & 63;
  int g = u >> 3, kt = u & 7;
  int q = g >> 1, mt = g & 1;
  int row = q * 256 + 32 * w + 16 * mt + (lane & 15);
  int k0 = kt * 32 + (lane >> 4) * 8;
  const float* src = (mat == 0 ? s0 : mat == 1 ? s1 : s2) + row * 256 + k0;
  v8h v;
#pragma unroll
  for (int j = 0; j < 8; ++j) v[j] = (_Float16)src[j];
  dst[idx] = v;
}

__global__ __launch_bounds__(512) __attribute__((amdgpu_waves_per_eu(2, 2)))
void decoder_mfma3(
    const float* __restrict__ seq, const float* __restrict__ z,
    const float* __restrict__ wih0, const float* __restrict__ bih0,
    const float* __restrict__ bhh0, const float* __restrict__ bih1,
    const float* __restrict__ bhh1, const float* __restrict__ wout,
    const float* __restrict__ bout, const v8h* __restrict__ pack,
    float* __restrict__ loss_out) {
  __shared__ alignas(16) _Float16 hbuf[4][16 * 256];  // 32 KB, XOR-swizzled
  __shared__ float lb0[1024], lw0[1024], lb1[1024];   // 12 KB
  __shared__ float sseq[kM][kT + 1];                  // 16.4 KB fp32
  __shared__ float lspred[8 * kM];
  __shared__ float lx[16];

  const int tid = threadIdx.x;
  const int w = tid >> 6;  // wave 0..7 -> h-rows [32w, 32w+32)
  const int l = tid & 63;
  const int n = l & 15;    // batch lane (cols >= kM are dead)
  const int kg = l >> 4;
  const int b0 = blockIdx.x * kM;

  for (int i = tid; i < 1024; i += 512) {
    lb0[i] = bih0[i] + bhh0[i];
    lw0[i] = wih0[i];
    lb1[i] = bih1[i] + bhh1[i];
  }
  for (int i = tid; i < kM * kT; i += 512) {
    int bb = i >> 9, tt = i & 511;
    sseq[bb][tt] = seq[(size_t)(b0 + bb) * kT + tt];
  }
  for (int i = tid; i < 16 * 256; i += 512) {
    int bb = i >> 8, k = i & 255;
    _Float16 hv = (bb < kM) ? (_Float16)z[(size_t)(b0 + bb) * kH + k] : (_Float16)0.f;
    int addr = bb * 256 + ((((k >> 3) ^ (bb & 7))) << 3) + (k & 7);
    hbuf[0][addr] = hv;
    hbuf[2][addr] = hv;
  }
  if (tid < 16) lx[tid] = 0.f;

  const int zn = (n < kM) ? n : (kM - 1);  // clamp dead lanes (no OOB)
  float c0[2][4], c1[2][4], wr[2][4];
#pragma unroll
  for (int mt = 0; mt < 2; ++mt)
#pragma unroll
    for (int r = 0; r < 4; ++r) {
      int row = 32 * w + 16 * mt + 4 * kg + r;
      float zv = z[(size_t)(b0 + zn) * kH + row];
      c0[mt][r] = zv;
      c1[mt][r] = zv;
      wr[mt][r] = wout[row];
    }
  const float bo = bout[0];
  float lacc = 0.f;
  __syncthreads();

  // per-wave linear stream: frag s at ap[s*64]; chunk c = frags [4c, 4c+4)
  const v8h* ap = pack + (size_t)(w * 192) * 64 + l;
  v8h af[16];  // 4-slot ring of 4-frag chunks
#pragma unroll
  for (int c = 0; c < 3; ++c)
#pragma unroll
    for (int i = 0; i < 4; ++i) af[c * 4 + i] = ap[(c * 4 + i) * 64];

  for (int t = 0; t < kT; ++t) {
    const int p = t & 1;
    const _Float16* h0r = hbuf[p];
    _Float16* h0w = hbuf[1 - p];
    const _Float16* h1r = hbuf[2 + p];
    _Float16* h1w = hbuf[3 - p];

    v4f ac[8];
    v8h bf[8];
    float x = lx[n];

    // ================= phase L0: chunks 0..15 (Whh0) =================
#pragma unroll
    for (int kt = 0; kt < 8; ++kt)
      bf[kt] = *(const v8h*)&h0r[(n << 8) + ((((kt << 2) + kg) ^ (n & 7)) << 3)];
#pragma unroll
    for (int c = 0; c < 16; ++c) {
      const int pc = c + 3, ps = pc % 48, rs = pc & 3, cs = c & 3;
#pragma unroll
      for (int i = 0; i < 4; ++i) af[rs * 4 + i] = ap[(ps * 4 + i) * 64];
      const int g = c >> 1, half = c & 1;
      if (half == 0) ac[g] = v4f{0.f, 0.f, 0.f, 0.f};
#pragma unroll
      for (int i = 0; i < 4; ++i)
        ac[g] = __builtin_amdgcn_mfma_f32_16x16x32_f16(af[cs * 4 + i],
                                                       bf[half * 4 + i], ac[g], 0, 0, 0);
    }
#pragma unroll
    for (int mt = 0; mt < 2; ++mt) {
      v4h hv;
#pragma unroll
      for (int r = 0; r < 4; ++r) {
        int rb = 32 * w + 16 * mt + 4 * kg + r;
        float pi = ac[0 + mt][r] + lb0[rb] + x * lw0[rb];
        float pf = ac[2 + mt][r] + lb0[256 + rb] + x * lw0[256 + rb];
        float pg = ac[4 + mt][r] + lb0[512 + rb] + x * lw0[512 + rb];
        float po = ac[6 + mt][r] + lb0[768 + rb] + x * lw0[768 + rb];
        c0[mt][r] = fsig(pf) * c0[mt][r] + fsig(pi) * ftanh(pg);
        hv[r] = (_Float16)(fsig(po) * ftanh(c0[mt][r]));
      }
      int addr = (n << 8) + (((4 * w + 2 * mt + (kg >> 1)) ^ (n & 7)) << 3) +
                 ((kg & 1) << 2);
      *(v4h*)&h0w[addr] = hv;
    }
    __syncthreads();  // barrier 1: h0(t) visible

    // ================= phase L1a: chunks 16..31 (Wih1 @ h0new) =======
#pragma unroll
    for (int kt = 0; kt < 8; ++kt)
      bf[kt] = *(const v8h*)&h0w[(n << 8) + ((((kt << 2) + kg) ^ (n & 7)) << 3)];
#pragma unroll
    for (int c = 16; c < 32; ++c) {
      const int pc = c + 3, ps = pc % 48, rs = pc & 3, cs = c & 3;
#pragma unroll
      for (int i = 0; i < 4; ++i) af[rs * 4 + i] = ap[(ps * 4 + i) * 64];
      const int g = (c - 16) >> 1, half = c & 1;
      if (half == 0) ac[g] = v4f{0.f, 0.f, 0.f, 0.f};
#pragma unroll
      for (int i = 0; i < 4; ++i)
        ac[g] = __builtin_amdgcn_mfma_f32_16x16x32_f16(af[cs * 4 + i],
                                                       bf[half * 4 + i], ac[g], 0, 0, 0);
    }
    // ================= phase L1b: chunks 32..47 (Whh1 @ h1old) =======
#pragma unroll
    for (int kt = 0; kt < 8; ++kt)
      bf[kt] = *(const v8h*)&h1r[(n << 8) + ((((kt << 2) + kg) ^ (n & 7)) << 3)];
#pragma unroll
    for (int c = 32; c < 48; ++c) {
      const int pc = c + 3, ps = pc % 48, rs = pc & 3, cs = c & 3;
#pragma unroll
      for (int i = 0; i < 4; ++i) af[rs * 4 + i] = ap[(ps * 4 + i) * 64];
      const int g = (c - 32) >> 1, half = c & 1;
#pragma unroll
      for (int i = 0; i < 4; ++i)
        ac[g] = __builtin_amdgcn_mfma_f32_16x16x32_f16(af[cs * 4 + i],
                                                       bf[half * 4 + i], ac[g], 0, 0, 0);
    }
    {
      float pp = 0.f;
#pragma unroll
      for (int mt = 0; mt < 2; ++mt) {
        v4h hv;
#pragma unroll
        for (int r = 0; r < 4; ++r) {
          int rb = 32 * w + 16 * mt + 4 * kg + r;
          float pi = ac[0 + mt][r] + lb1[rb];
          float pf = ac[2 + mt][r] + lb1[256 + rb];
          float pg = ac[4 + mt][r] + lb1[512 + rb];
          float po = ac[6 + mt][r] + lb1[768 + rb];
          c1[mt][r] = fsig(pf) * c1[mt][r] + fsig(pi) * ftanh(pg);
          float hn = fsig(po) * ftanh(c1[mt][r]);
          hv[r] = (_Float16)hn;
          pp = fmaf(hn, wr[mt][r], pp);
        }
        int addr = (n << 8) + (((4 * w + 2 * mt + (kg >> 1)) ^ (n & 7)) << 3) +
                   ((kg & 1) << 2);
        *(v4h*)&h1w[addr] = hv;
      }
      pp += __shfl_xor(pp, 16);
      pp += __shfl_xor(pp, 32);
      if (l < kM) lspred[w * kM + l] = pp;
    }
    __syncthreads();  // barrier 2: h1(t) + pred partials visible

    if (tid < kM) {
      float pred = bo;
#pragma unroll
      for (int ww = 0; ww < 8; ++ww) pred += lspred[ww * kM + tid];
      float d = sseq[tid][t] - pred;
      lacc = fmaf(d, d, lacc);
      lx[tid] = pred;
    }
    __syncthreads();  // barrier 3: x(t) stable
  }

  if (tid < kM) atomicAdd(loss_out, lacc * (1.0f / ((float)kB * (float)kT)));
}

// ---------------- fallback (round-1 structure, no workspace needed) --------
__global__ __launch_bounds__(1024) void decoder_fallback(
    const float* __restrict__ seq, const float* __restrict__ z,
    const float* __restrict__ wih0, const float* __restrict__ bih0,
    const float* __restrict__ bhh0, const float* __restrict__ whh0,
    const float* __restrict__ wih1, const float* __restrict__ whh1,
    const float* __restrict__ bih1, const float* __restrict__ bhh1,
    const float* __restrict__ wout, const float* __restrict__ bout,
    float* __restrict__ loss_out) {
  __shared__ float h0s[kH], h1s[kH], g4[1024];
  __shared__ float xs_s;
  const int tid = threadIdx.x;
  const int b = blockIdx.x;
  float c0r = 0.f, c1r = 0.f;
  if (tid < kH) {
    float zv = z[b * kH + tid];
    h0s[tid] = zv; h1s[tid] = zv; c0r = zv; c1r = zv;
  }
  if (tid == 0) xs_s = 0.f;
  const float wih0_j = wih0[tid];
  const float bias0_j = bih0[tid] + bhh0[tid];
  const float bias1_j = bih1[tid] + bhh1[tid];
  const float wout_r = (tid < kH) ? wout[tid] : 0.f;
  const float bo = bout[0];
  float lacc = 0.f;
  __syncthreads();
  for (int t = 0; t < kT; ++t) {
    float a0 = fmaf(xs_s, wih0_j, bias0_j);
    for (int k = 0; k < kH; ++k) a0 = fmaf(whh0[tid * kH + k], h0s[k], a0);
    g4[tid] = a0;
    __syncthreads();
    if (tid < kH) {
      float ig = fsig(g4[tid]), fg = fsig(g4[tid + 256]);
      float gg = ftanh(g4[tid + 512]), og = fsig(g4[tid + 768]);
      c0r = fmaf(fg, c0r, ig * gg);
      h0s[tid] = og * ftanh(c0r);
    }
    __syncthreads();
    float a1 = bias1_j;
    for (int k = 0; k < kH; ++k) a1 = fmaf(wih1[tid * kH + k], h0s[k], a1);
    for (int k = 0; k < kH; ++k) a1 = fmaf(whh1[tid * kH + k], h1s[k], a1);
    g4[tid] = a1;
    __syncthreads();
    if (tid < kH) {
      float ig = fsig(g4[tid]), fg = fsig(g4[tid + 256]);
      float gg = ftanh(g4[tid + 512]), og = fsig(g4[tid + 768]);
      c1r = fmaf(fg, c1r, ig * gg);
      float h1 = og * ftanh(c1r);
      h1s[tid] = h1;
      g4[tid] = h1 * wout_r;
    }
    __syncthreads();
    if (tid < 64) {
      float v = g4[tid] + g4[tid + 64] + g4[tid + 128] + g4[tid + 192];
#pragma unroll
      for (int off = 32; off > 0; off >>= 1) v += __shfl_down(v, off);
      if (tid == 0) {
        float pred = v + bo;
        float d = seq[b * kT + t] - pred;
        lacc = fmaf(d, d, lacc);
        xs_s = pred;
      }
    }
    __syncthreads();
  }
  if (tid == 0) atomicAdd(loss_out, lacc * (1.0f / (float)(kB * kT)));
}

}  // namespace

extern "C" void kernel_launch(void* const* d_in, const int* in_sizes, int n_in,
                              void* d_out, int out_size, void* d_ws, size_t ws_size,
                              hipStream_t stream) {
  const float* seq = (const float*)d_in[0];
  const float* z = (const float*)d_in[1];
  const float* wih0 = (const float*)d_in[3];
  const float* whh0 = (const float*)d_in[4];
  const float* bih0 = (const float*)d_in[5];
  const float* bhh0 = (const float*)d_in[6];
  const float* wih1 = (const float*)d_in[7];
  const float* whh1 = (const float*)d_in[8];
  const float* bih1 = (const float*)d_in[9];
  const float* bhh1 = (const float*)d_in[10];
  const float* wout = (const float*)d_in[11];
  const float* bout = (const float*)d_in[12];
  float* out = (float*)d_out;

  hipMemsetAsync(out, 0, sizeof(float), stream);

  if (ws_size >= kWsNeeded) {
    v8h* wpk = (v8h*)d_ws;
    pack_frag2<<<384, 256, 0, stream>>>(whh0, wih1, whh1, wpk);
    decoder_mfma3<<<32, 512, 0, stream>>>(seq, z, wih0, bih0, bhh0, bih1, bhh1,
                                          wout, bout, wpk, out);
  } else {
    decoder_fallback<<<kB, 1024, 0, stream>>>(seq, z, wih0, bih0, bhh0, whh0,
                                              wih1, whh1, bih1, bhh1, wout, bout,
                                              out);
  }
}

// Round 7
// 15158.171 us; speedup vs baseline: 1.6492x; 1.6492x over previous
//
#include <hip/hip_runtime.h>

// Decoder: 2-layer LSTM (H=256), T=512, B=256, scalar output feedback.
// Round 7: MFMA with LDS-DMA weight pipeline. 16 blocks x 512 threads, M=16
// (proven L2-resident config from r5). Each wave streams its contiguous
// per-wave fp16 A-fragment stream (192 KB/step) through a private 4-slot x
// 2KB LDS ring using __builtin_amdgcn_global_load_lds (16B/lane) + manual
// s_waitcnt vmcnt(4) -- sidesteps the compiler's register-pipeline collapse
// that pinned rounds 4-6 at VGPR=128 with zero memory-level parallelism.

namespace {

typedef _Float16 v8h __attribute__((ext_vector_type(8)));
typedef _Float16 v4h __attribute__((ext_vector_type(4)));
typedef float v4f __attribute__((ext_vector_type(4)));

constexpr int kB = 256, kT = 512, kH = 256;
constexpr int kFragsPerWave = 192;                 // per wave per step
constexpr int kTotFrags = 8 * kFragsPerWave * 64;  // 98304 v8h
constexpr size_t kWsNeeded = (size_t)kTotFrags * sizeof(v8h);  // 1.5 MB

// dyn-LDS layout (bytes): astage 65536 | hbuf 32768 | lb0/lw0/lb1 12288 |
// sseq 16*513*4 | lspred 512 | lx 64  => 144000 total
constexpr int kLdsBytes = 65536 + 32768 + 12288 + 16 * 513 * 4 + 512 + 64;

#define WAITVM(N) \
  __builtin_amdgcn_s_waitcnt((((N) & 0xF) | (((N) >> 4) << 14) | 0x70 | 0xF00))

__device__ __forceinline__ float fsig(float v) {
  return __builtin_amdgcn_rcpf(1.f + __expf(-v));
}
__device__ __forceinline__ float ftanh(float v) {
  return 1.f - 2.f * __builtin_amdgcn_rcpf(1.f + __expf(2.f * v));
}

__device__ __forceinline__ void dma16(const v8h* g, _Float16* l) {
  __builtin_amdgcn_global_load_lds(
      (const __attribute__((address_space(1))) void*)g,
      (__attribute__((address_space(3))) void*)l, 16, 0, 0);
}

// Per-wave contiguous fp16 A-fragment streams (same as r6):
// dst[(w*192 + s)*64 + lane], s = mat*64 + g*8 + kt, g = q*2 + mt;
// lane holds W[q*256 + 32w + 16mt + (lane&15)][kt*32 + (lane>>4)*8 + j].
__global__ __launch_bounds__(256) void pack_frag2(const float* __restrict__ s0,
                                                  const float* __restrict__ s1,
                                                  const float* __restrict__ s2,
                                                  v8h* __restrict__ dst) {
  int idx = blockIdx.x * 256 + threadIdx.x;  // 0 .. 98303
  int lane = idx & 63;
  int sw = idx >> 6;
  int s = sw % 192, w = sw / 192;
  int mat = s >> 6, u = s & 63;
  int g = u >> 3, kt = u & 7;
  int q = g >> 1, mt = g & 1;
  int row = q * 256 + 32 * w + 16 * mt + (lane & 15);
  int k0 = kt * 32 + (lane >> 4) * 8;
  const float* src = (mat == 0 ? s0 : mat == 1 ? s1 : s2) + row * 256 + k0;
  v8h v;
#pragma unroll
  for (int j = 0; j < 8; ++j) v[j] = (_Float16)src[j];
  dst[idx] = v;
}

__global__ __launch_bounds__(512) void decoder_mfma4(
    const float* __restrict__ seq, const float* __restrict__ z,
    const float* __restrict__ wih0, const float* __restrict__ bih0,
    const float* __restrict__ bhh0, const float* __restrict__ bih1,
    const float* __restrict__ bhh1, const float* __restrict__ wout,
    const float* __restrict__ bout, const v8h* __restrict__ pack,
    float* __restrict__ loss_out) {
  extern __shared__ __align__(16) char smem[];
  _Float16* astage = (_Float16*)smem;              // 8 waves x 4 slots x 1024 halves
  _Float16* hbase = (_Float16*)(smem + 65536);     // 4 bufs x 4096 halves (swizzled)
  float* lb0 = (float*)(smem + 65536 + 32768);
  float* lw0 = lb0 + 1024;
  float* lb1 = lw0 + 1024;
  float* sseq = lb1 + 1024;         // [16][513]
  float* lspred = sseq + 16 * 513;  // [8][16]
  float* lx = lspred + 128;         // [16]

  const int tid = threadIdx.x;
  const int w = tid >> 6, l = tid & 63;
  const int n = l & 15, kg = l >> 4;
  const int b0 = blockIdx.x * 16;

  for (int i = tid; i < 1024; i += 512) {
    lb0[i] = bih0[i] + bhh0[i];
    lw0[i] = wih0[i];
    lb1[i] = bih1[i] + bhh1[i];
  }
  for (int i = tid; i < 16 * kT; i += 512) {
    int bb = i >> 9, tt = i & 511;
    sseq[bb * 513 + tt] = seq[(size_t)(b0 + bb) * kT + tt];
  }
  for (int i = tid; i < 16 * 256; i += 512) {
    int bb = i >> 8, k = i & 255;
    _Float16 hv = (_Float16)z[(size_t)(b0 + bb) * kH + k];
    int addr = bb * 256 + ((((k >> 3) ^ (bb & 7))) << 3) + (k & 7);
    hbase[addr] = hv;             // h0 parity 0
    hbase[2 * 4096 + addr] = hv;  // h1 parity 0
  }
  if (tid < 16) lx[tid] = 0.f;

  float c0[2][4], c1[2][4], wr[2][4];
#pragma unroll
  for (int mt = 0; mt < 2; ++mt)
#pragma unroll
    for (int r = 0; r < 4; ++r) {
      int row = 32 * w + 16 * mt + 4 * kg + r;
      float zv = z[(size_t)(b0 + n) * kH + row];
      c0[mt][r] = zv;
      c1[mt][r] = zv;
      wr[mt][r] = wout[row];
    }
  const float bo = bout[0];
  float lacc = 0.f;
  __syncthreads();

  const v8h* gstream = pack + (size_t)(w * kFragsPerWave) * 64 + l;
  _Float16* sb = astage + w * 4096;  // this wave's 4-slot ring (halves)

  // initial prefetch: chunks 0..2 (each chunk = 2 frags = 2 DMA instrs)
#pragma unroll
  for (int c = 0; c < 3; ++c) {
    const v8h* g0 = gstream + (2 * c) * 64;
    dma16(g0, sb + c * 1024);
    dma16(g0 + 64, sb + c * 1024 + 512);
  }

  v4f ac[8];
  v8h bf[8];

  for (int t = 0; t < kT; ++t) {
    const int p = t & 1;
    const _Float16* h0r = hbase + p * 4096;
    _Float16* h0w = hbase + (1 - p) * 4096;
    const _Float16* h1r = hbase + (2 + p) * 4096;
    _Float16* h1w = hbase + (3 - p) * 4096;

    // ============ phase L0: chunks 0..31 (Whh0 @ h0) ============
#pragma unroll
    for (int kt = 0; kt < 8; ++kt)
      bf[kt] = *(const v8h*)&h0r[(n << 8) + ((((kt << 2) + kg) ^ (n & 7)) << 3)];
#pragma unroll
    for (int c = 0; c < 32; ++c) {
      WAITVM(4);  // chunk c landed (c+1, c+2 still in flight)
      const _Float16* rb = sb + (c & 3) * 1024 + (l << 3);
      v8h a0 = *(const v8h*)rb;
      v8h a1 = *(const v8h*)(rb + 512);
      const int g = c >> 2, kt = 2 * (c & 3);
      if ((c & 3) == 0) ac[g] = v4f{0.f, 0.f, 0.f, 0.f};
      ac[g] = __builtin_amdgcn_mfma_f32_16x16x32_f16(a0, bf[kt], ac[g], 0, 0, 0);
      ac[g] = __builtin_amdgcn_mfma_f32_16x16x32_f16(a1, bf[kt + 1], ac[g], 0, 0, 0);
      const int pc = c + 3;  // always < 96
      const v8h* g0 = gstream + (2 * pc) * 64;
      _Float16* lbp = sb + (pc & 3) * 1024;
      dma16(g0, lbp);
      dma16(g0 + 64, lbp + 512);
    }
    {
      float x = lx[n];
#pragma unroll
      for (int mt = 0; mt < 2; ++mt) {
        v4h hv;
#pragma unroll
        for (int r = 0; r < 4; ++r) {
          int rb = 32 * w + 16 * mt + 4 * kg + r;
          float pi = ac[0 + mt][r] + lb0[rb] + x * lw0[rb];
          float pf = ac[2 + mt][r] + lb0[256 + rb] + x * lw0[256 + rb];
          float pg = ac[4 + mt][r] + lb0[512 + rb] + x * lw0[512 + rb];
          float po = ac[6 + mt][r] + lb0[768 + rb] + x * lw0[768 + rb];
          c0[mt][r] = fsig(pf) * c0[mt][r] + fsig(pi) * ftanh(pg);
          hv[r] = (_Float16)(fsig(po) * ftanh(c0[mt][r]));
        }
        int addr = (n << 8) + (((4 * w + 2 * mt + (kg >> 1)) ^ (n & 7)) << 3) +
                   ((kg & 1) << 2);
        *(v4h*)&h0w[addr] = hv;
      }
    }
    __syncthreads();  // barrier 1: h0(t) visible (drains vmcnt; data kept in LDS)

    // ============ phase L1a: chunks 32..63 (Wih1 @ h0new) ============
#pragma unroll
    for (int kt = 0; kt < 8; ++kt)
      bf[kt] = *(const v8h*)&h0w[(n << 8) + ((((kt << 2) + kg) ^ (n & 7)) << 3)];
#pragma unroll
    for (int c = 32; c < 64; ++c) {
      WAITVM(4);
      const _Float16* rb = sb + (c & 3) * 1024 + (l << 3);
      v8h a0 = *(const v8h*)rb;
      v8h a1 = *(const v8h*)(rb + 512);
      const int lc = c & 31, g = lc >> 2, kt = 2 * (lc & 3);
      if ((lc & 3) == 0) ac[g] = v4f{0.f, 0.f, 0.f, 0.f};
      ac[g] = __builtin_amdgcn_mfma_f32_16x16x32_f16(a0, bf[kt], ac[g], 0, 0, 0);
      ac[g] = __builtin_amdgcn_mfma_f32_16x16x32_f16(a1, bf[kt + 1], ac[g], 0, 0, 0);
      const int pc = c + 3;
      const v8h* g0 = gstream + (2 * pc) * 64;
      _Float16* lbp = sb + (pc & 3) * 1024;
      dma16(g0, lbp);
      dma16(g0 + 64, lbp + 512);
    }
    // ============ phase L1b: chunks 64..95 (+= Whh1 @ h1old) ============
#pragma unroll
    for (int kt = 0; kt < 8; ++kt)
      bf[kt] = *(const v8h*)&h1r[(n << 8) + ((((kt << 2) + kg) ^ (n & 7)) << 3)];
#pragma unroll
    for (int c = 64; c < 96; ++c) {
      WAITVM(4);
      const _Float16* rb = sb + (c & 3) * 1024 + (l << 3);
      v8h a0 = *(const v8h*)rb;
      v8h a1 = *(const v8h*)(rb + 512);
      const int lc = c & 31, g = lc >> 2, kt = 2 * (lc & 3);
      ac[g] = __builtin_amdgcn_mfma_f32_16x16x32_f16(a0, bf[kt], ac[g], 0, 0, 0);
      ac[g] = __builtin_amdgcn_mfma_f32_16x16x32_f16(a1, bf[kt + 1], ac[g], 0, 0, 0);
      const int pc = (c + 3) % 96;  // wrap: prefetch next step's chunks 0..2
      const v8h* g0 = gstream + (2 * pc) * 64;
      _Float16* lbp = sb + (pc & 3) * 1024;  // 96%4==0 keeps slots aligned
      dma16(g0, lbp);
      dma16(g0 + 64, lbp + 512);
    }
    {
      float pp = 0.f;
#pragma unroll
      for (int mt = 0; mt < 2; ++mt) {
        v4h hv;
#pragma unroll
        for (int r = 0; r < 4; ++r) {
          int rb = 32 * w + 16 * mt + 4 * kg + r;
          float pi = ac[0 + mt][r] + lb1[rb];
          float pf = ac[2 + mt][r] + lb1[256 + rb];
          float pg = ac[4 + mt][r] + lb1[512 + rb];
          float po = ac[6 + mt][r] + lb1[768 + rb];
          c1[mt][r] = fsig(pf) * c1[mt][r] + fsig(pi) * ftanh(pg);
          float hn = fsig(po) * ftanh(c1[mt][r]);
          hv[r] = (_Float16)hn;
          pp = fmaf(hn, wr[mt][r], pp);
        }
        int addr = (n << 8) + (((4 * w + 2 * mt + (kg >> 1)) ^ (n & 7)) << 3) +
                   ((kg & 1) << 2);
        *(v4h*)&h1w[addr] = hv;
      }
      pp += __shfl_xor(pp, 16);
      pp += __shfl_xor(pp, 32);
      if (l < 16) lspred[w * 16 + l] = pp;
    }
    __syncthreads();  // barrier 2: h1(t) + pred partials visible

    if (tid < 16) {
      float pred = bo;
#pragma unroll
      for (int ww = 0; ww < 8; ++ww) pred += lspred[ww * 16 + tid];
      float d = sseq[tid * 513 + t] - pred;
      lacc = fmaf(d, d, lacc);
      lx[tid] = pred;
    }
    __syncthreads();  // barrier 3: x(t) stable
  }

  WAITVM(0);  // drain trailing prefetches before wave exit
  if (tid < 16) atomicAdd(loss_out, lacc * (1.0f / ((float)kB * (float)kT)));
}

// ---------------- fallback (round-1 structure, no workspace needed) --------
__global__ __launch_bounds__(1024) void decoder_fallback(
    const float* __restrict__ seq, const float* __restrict__ z,
    const float* __restrict__ wih0, const float* __restrict__ bih0,
    const float* __restrict__ bhh0, const float* __restrict__ whh0,
    const float* __restrict__ wih1, const float* __restrict__ whh1,
    const float* __restrict__ bih1, const float* __restrict__ bhh1,
    const float* __restrict__ wout, const float* __restrict__ bout,
    float* __restrict__ loss_out) {
  __shared__ float h0s[kH], h1s[kH], g4[1024];
  __shared__ float xs_s;
  const int tid = threadIdx.x;
  const int b = blockIdx.x;
  float c0r = 0.f, c1r = 0.f;
  if (tid < kH) {
    float zv = z[b * kH + tid];
    h0s[tid] = zv; h1s[tid] = zv; c0r = zv; c1r = zv;
  }
  if (tid == 0) xs_s = 0.f;
  const float wih0_j = wih0[tid];
  const float bias0_j = bih0[tid] + bhh0[tid];
  const float bias1_j = bih1[tid] + bhh1[tid];
  const float wout_r = (tid < kH) ? wout[tid] : 0.f;
  const float bo = bout[0];
  float lacc = 0.f;
  __syncthreads();
  for (int t = 0; t < kT; ++t) {
    float a0 = fmaf(xs_s, wih0_j, bias0_j);
    for (int k = 0; k < kH; ++k) a0 = fmaf(whh0[tid * kH + k], h0s[k], a0);
    g4[tid] = a0;
    __syncthreads();
    if (tid < kH) {
      float ig = fsig(g4[tid]), fg = fsig(g4[tid + 256]);
      float gg = ftanh(g4[tid + 512]), og = fsig(g4[tid + 768]);
      c0r = fmaf(fg, c0r, ig * gg);
      h0s[tid] = og * ftanh(c0r);
    }
    __syncthreads();
    float a1 = bias1_j;
    for (int k = 0; k < kH; ++k) a1 = fmaf(wih1[tid * kH + k], h0s[k], a1);
    for (int k = 0; k < kH; ++k) a1 = fmaf(whh1[tid * kH + k], h1s[k], a1);
    g4[tid] = a1;
    __syncthreads();
    if (tid < kH) {
      float ig = fsig(g4[tid]), fg = fsig(g4[tid + 256]);
      float gg = ftanh(g4[tid + 512]), og = fsig(g4[tid + 768]);
      c1r = fmaf(fg, c1r, ig * gg);
      float h1 = og * ftanh(c1r);
      h1s[tid] = h1;
      g4[tid] = h1 * wout_r;
    }
    __syncthreads();
    if (tid < 64) {
      float v = g4[tid] + g4[tid + 64] + g4[tid + 128] + g4[tid + 192];
#pragma unroll
      for (int off = 32; off > 0; off >>= 1) v += __shfl_down(v, off);
      if (tid == 0) {
        float pred = v + bo;
        float d = seq[b * kT + t] - pred;
        lacc = fmaf(d, d, lacc);
        xs_s = pred;
      }
    }
    __syncthreads();
  }
  if (tid == 0) atomicAdd(loss_out, lacc * (1.0f / (float)(kB * kT)));
}

}  // namespace

extern "C" void kernel_launch(void* const* d_in, const int* in_sizes, int n_in,
                              void* d_out, int out_size, void* d_ws, size_t ws_size,
                              hipStream_t stream) {
  const float* seq = (const float*)d_in[0];
  const float* z = (const float*)d_in[1];
  const float* wih0 = (const float*)d_in[3];
  const float* whh0 = (const float*)d_in[4];
  const float* bih0 = (const float*)d_in[5];
  const float* bhh0 = (const float*)d_in[6];
  const float* wih1 = (const float*)d_in[7];
  const float* whh1 = (const float*)d_in[8];
  const float* bih1 = (const float*)d_in[9];
  const float* bhh1 = (const float*)d_in[10];
  const float* wout = (const float*)d_in[11];
  const float* bout = (const float*)d_in[12];
  float* out = (float*)d_out;

  hipMemsetAsync(out, 0, sizeof(float), stream);

  if (ws_size >= kWsNeeded) {
    v8h* wpk = (v8h*)d_ws;
    pack_frag2<<<384, 256, 0, stream>>>(whh0, wih1, whh1, wpk);
    decoder_mfma4<<<16, 512, kLdsBytes, stream>>>(seq, z, wih0, bih0, bhh0,
                                                  bih1, bhh1, wout, bout, wpk,
                                                  out);
  } else {
    decoder_fallback<<<kB, 1024, 0, stream>>>(seq, z, wih0, bih0, bhh0, whh0,
                                              wih1, whh1, bih1, bhh1, wout, bout,
                                              out);
  }
}